// Round 5
// baseline (49.050 us; speedup 1.0000x reference)
//
#include <hip/hip_runtime.h>

#define BSZ 8192
#define DIM 128
#define MARGIN 0.3f
#define EPS 1e-8f
#define NJ 32              // j-splits
#define JCHUNK 256         // BSZ / NJ
#define NPH 8              // phases per block (32 cols each)

typedef __bf16 bf16x8 __attribute__((ext_vector_type(8)));
typedef float f32x4 __attribute__((ext_vector_type(4)));

#define AS1 __attribute__((address_space(1)))
#define AS3 __attribute__((address_space(3)))

// order-preserving float <-> uint key (works for negative values)
__device__ __forceinline__ unsigned enc_ord(float f) {
    unsigned u = __float_as_uint(f);
    return (u & 0x80000000u) ? ~u : (u | 0x80000000u);
}
__device__ __forceinline__ float dec_ord(unsigned e) {
    unsigned u = (e & 0x80000000u) ? (e & 0x7FFFFFFFu) : ~e;
    return __uint_as_float(u);
}

// ws layout: __bf16 hi[8192*128]; float sq[8192]; uint maxp[8192]; uint minn[8192];
//            {float sum; uint cnt}
// maxp/minn hold enc_ord(key), key = max/min over j of (sqj - 2*dot(i,j))

__global__ __launch_bounds__(256) void k_prep(const float* __restrict__ emb,
                                              __bf16* __restrict__ hi,
                                              float* __restrict__ sq,
                                              unsigned* __restrict__ maxp,
                                              unsigned* __restrict__ minn,
                                              float* __restrict__ sumcnt) {
    int row = blockIdx.x * 4 + (threadIdx.x >> 6);
    int lane = threadIdx.x & 63;
    float2 v = *(const float2*)&emb[(size_t)row * DIM + lane * 2];
    union { __bf16 b[2]; unsigned u; } p;
    p.b[0] = (__bf16)v.x;
    p.b[1] = (__bf16)v.y;
    ((unsigned*)hi)[row * 64 + lane] = p.u;
    float s = v.x * v.x + v.y * v.y;
#pragma unroll
    for (int m = 32; m >= 1; m >>= 1) s += __shfl_xor(s, m);
    if (lane == 0) {
        sq[row] = s;
        maxp[row] = 0u;            // < enc_ord of any real float
        minn[row] = 0xFFFFFFFFu;   // > enc_ord of any real float
    }
    if (blockIdx.x == 0 && threadIdx.x == 0) {
        sumcnt[0] = 0.0f;
        ((unsigned*)sumcnt)[1] = 0u;
    }
}

// Block: 4 waves, 128 anchor rows (2 x 16-row tiles per wave).
// Phase: 32 j-cols = 2 B-tiles (8 K-frags), LDS double-buffered via
// global_load_lds (pre-swizzled source -> linear frag order), shared by all waves.
// Per wave-phase: 8 ds_read_b128 -> 16 MFMA (4 indep chains of 4) -> 16-elem epilogue.
__global__ __launch_bounds__(256, 4) void k_mfma(const __bf16* __restrict__ hi,
                                                 const int* __restrict__ labels,
                                                 const float* __restrict__ sq,
                                                 unsigned* __restrict__ maxp,
                                                 unsigned* __restrict__ minn) {
    __shared__ char Bst[2][8][1024];   // [buf][frag m = jt*4+f][lane*16B]
    __shared__ float sqlds[JCHUNK];
    __shared__ int lablds[JCHUNK];

    const int tid = threadIdx.x;
    const int lane = tid & 63;
    const int wave = tid >> 6;
    const int lr = lane & 15;
    const int lq = lane >> 4;
    const int it0 = blockIdx.x * 128 + wave * 32;
    const int it1 = it0 + 16;
    const int j0 = blockIdx.y * JCHUNK;
    const float INF = __uint_as_float(0x7F800000u);

    sqlds[tid] = sq[j0 + tid];
    lablds[tid] = labels[j0 + tid];

    // A fragments: 2 i-tiles x 4 K-frags, register-resident (32 VGPR), pinned
    bf16x8 a0[4], a1[4];
    const __bf16* ap = hi + (size_t)(it0 + lr) * DIM + lq * 8;
#pragma unroll
    for (int f = 0; f < 4; ++f) {
        a0[f] = *(const bf16x8*)&ap[f * 32];
        a1[f] = *(const bf16x8*)&ap[16 * DIM + f * 32];
        asm volatile("" : "+v"(a0[f]));
        asm volatile("" : "+v"(a1[f]));
    }
    const int4 li0 = *(const int4*)&labels[it0 + lq * 4];
    const int4 li1 = *(const int4*)&labels[it1 + lq * 4];
    const int labi0[4] = {li0.x, li0.y, li0.z, li0.w};
    const int labi1[4] = {li1.x, li1.y, li1.z, li1.w};

    float mp0[4], mp1[4], mn0[4], mn1[4];
#pragma unroll
    for (int r = 0; r < 4; ++r) {
        mp0[r] = -INF; mp1[r] = -INF;
        mn0[r] = INF;  mn1[r] = INF;
    }

    // stage: wave w issues frag loads m0=2w, m1=2w+1 of the phase's 32-col tile.
    // frag m: j-subtile jt=m>>2, K-frag f=m&3.
    // src per-lane: emb_bf16[j0 + t*32 + jt*16 + (lane&15)][f*32 + (lane>>4)*8]
    const int m0 = wave * 2, m1 = m0 + 1;
    const __bf16* bsA = hi + (size_t)(j0 + (m0 >> 2) * 16 + lr) * DIM + (m0 & 3) * 32 + lq * 8;
    const __bf16* bsB = hi + (size_t)(j0 + (m1 >> 2) * 16 + lr) * DIM + (m1 & 3) * 32 + lq * 8;
#define STAGE(t, buf)                                                              \
    do {                                                                           \
        __builtin_amdgcn_global_load_lds(                                          \
            (const AS1 void*)(bsA + (size_t)(t) * 32 * DIM),                       \
            (AS3 void*)&Bst[buf][m0][0], 16, 0, 0);                                \
        __builtin_amdgcn_global_load_lds(                                          \
            (const AS1 void*)(bsB + (size_t)(t) * 32 * DIM),                       \
            (AS3 void*)&Bst[buf][m1][0], 16, 0, 0);                                \
    } while (0)

    STAGE(0, 0);
    __syncthreads();   // drains global_load_lds (vmcnt) + lut ds_writes

#pragma unroll 1
    for (int t = 0; t < NPH; ++t) {
        if (t + 1 < NPH) STAGE(t + 1, (t + 1) & 1);

        const float sqj0 = sqlds[t * 32 + lr];
        const float sqj1 = sqlds[t * 32 + 16 + lr];
        const int labj0 = lablds[t * 32 + lr];
        const int labj1 = lablds[t * 32 + 16 + lr];

        const bf16x8* bp = (const bf16x8*)&Bst[t & 1][0][0];
        f32x4 acc00 = {0, 0, 0, 0}, acc01 = {0, 0, 0, 0};
        f32x4 acc10 = {0, 0, 0, 0}, acc11 = {0, 0, 0, 0};
#pragma unroll
        for (int f = 0; f < 4; ++f) {
            bf16x8 b0 = bp[f * 64 + lane];
            bf16x8 b1 = bp[(4 + f) * 64 + lane];
            acc00 = __builtin_amdgcn_mfma_f32_16x16x32_bf16(a0[f], b0, acc00, 0, 0, 0);
            acc10 = __builtin_amdgcn_mfma_f32_16x16x32_bf16(a1[f], b0, acc10, 0, 0, 0);
            acc01 = __builtin_amdgcn_mfma_f32_16x16x32_bf16(a0[f], b1, acc01, 0, 0, 0);
            acc11 = __builtin_amdgcn_mfma_f32_16x16x32_bf16(a1[f], b1, acc11, 0, 0, 0);
        }

#pragma unroll
        for (int r = 0; r < 4; ++r) {
            float k00 = fmaf(-2.0f, acc00[r], sqj0);
            float k01 = fmaf(-2.0f, acc01[r], sqj1);
            float k10 = fmaf(-2.0f, acc10[r], sqj0);
            float k11 = fmaf(-2.0f, acc11[r], sqj1);
            bool s00 = (labj0 == labi0[r]);
            bool s01 = (labj1 == labi0[r]);
            bool s10 = (labj0 == labi1[r]);
            bool s11 = (labj1 == labi1[r]);
            mp0[r] = s00 ? fmaxf(mp0[r], k00) : mp0[r];
            mn0[r] = s00 ? mn0[r] : fminf(mn0[r], k00);
            mp0[r] = s01 ? fmaxf(mp0[r], k01) : mp0[r];
            mn0[r] = s01 ? mn0[r] : fminf(mn0[r], k01);
            mp1[r] = s10 ? fmaxf(mp1[r], k10) : mp1[r];
            mn1[r] = s10 ? mn1[r] : fminf(mn1[r], k10);
            mp1[r] = s11 ? fmaxf(mp1[r], k11) : mp1[r];
            mn1[r] = s11 ? mn1[r] : fminf(mn1[r], k11);
        }

        __syncthreads();   // auto vmcnt(0): next buffer staged; LDS safe to reuse
    }
#undef STAGE

    // reduce across the 16 cols (lr) within each lq quarter
#pragma unroll
    for (int m = 1; m < 16; m <<= 1) {
#pragma unroll
        for (int r = 0; r < 4; ++r) {
            mp0[r] = fmaxf(mp0[r], __shfl_xor(mp0[r], m));
            mn0[r] = fminf(mn0[r], __shfl_xor(mn0[r], m));
            mp1[r] = fmaxf(mp1[r], __shfl_xor(mp1[r], m));
            mn1[r] = fminf(mn1[r], __shfl_xor(mn1[r], m));
        }
    }
    if (lr == 0) {
#pragma unroll
        for (int r = 0; r < 4; ++r) {
            atomicMax(&maxp[it0 + lq * 4 + r], enc_ord(mp0[r]));
            atomicMin(&minn[it0 + lq * 4 + r], enc_ord(mn0[r]));
            atomicMax(&maxp[it1 + lq * 4 + r], enc_ord(mp1[r]));
            atomicMin(&minn[it1 + lq * 4 + r], enc_ord(mn1[r]));
        }
    }
}

__global__ __launch_bounds__(256) void k_final(const unsigned* __restrict__ maxp,
                                               const unsigned* __restrict__ minn,
                                               const float* __restrict__ sq,
                                               float* __restrict__ sumcnt) {
    int i = blockIdx.x * 256 + threadIdx.x;
    float mpd = dec_ord(maxp[i]);
    float mnd = dec_ord(minn[i]);
    float sqi = sq[i];
    bool valid = (mpd > -1e30f) && (mnd < 1e30f);
    float hp = sqrtf(fmaxf(sqi + mpd, 0.0f) + EPS);
    float hn = sqrtf(fmaxf(sqi + mnd, 0.0f) + EPS);
    float per = valid ? fmaxf(hp - hn + MARGIN, 0.0f) : 0.0f;
    unsigned cnt = valid ? 1u : 0u;
#pragma unroll
    for (int m = 32; m >= 1; m >>= 1) {
        per += __shfl_xor(per, m);
        cnt += __shfl_xor(cnt, m);
    }
    __shared__ float ssum[4];
    __shared__ unsigned scnt[4];
    int wid = threadIdx.x >> 6;
    if ((threadIdx.x & 63) == 0) { ssum[wid] = per; scnt[wid] = cnt; }
    __syncthreads();
    if (threadIdx.x == 0) {
        float s = ssum[0] + ssum[1] + ssum[2] + ssum[3];
        unsigned c = scnt[0] + scnt[1] + scnt[2] + scnt[3];
        atomicAdd(&sumcnt[0], s);
        atomicAdd((unsigned*)&sumcnt[1], c);
    }
}

__global__ void k_out(const float* __restrict__ sumcnt, float* __restrict__ out) {
    if (threadIdx.x == 0) {
        float s = sumcnt[0];
        unsigned c = ((const unsigned*)sumcnt)[1];
        out[0] = s / (float)(c > 0u ? c : 1u);
    }
}

extern "C" void kernel_launch(void* const* d_in, const int* in_sizes, int n_in,
                              void* d_out, int out_size, void* d_ws, size_t ws_size,
                              hipStream_t stream) {
    const float* emb    = (const float*)d_in[0];
    const int*   labels = (const int*)d_in[1];

    __bf16* hi = (__bf16*)d_ws;
    float*  sq = (float*)(hi + (size_t)BSZ * DIM);
    unsigned* maxp = (unsigned*)(sq + BSZ);
    unsigned* minn = maxp + BSZ;
    float* sumcnt = (float*)(minn + BSZ);
    float* out = (float*)d_out;

    k_prep<<<dim3(BSZ / 4), dim3(256), 0, stream>>>(emb, hi, sq, maxp, minn, sumcnt);
    k_mfma<<<dim3(BSZ / 128, NJ), dim3(256), 0, stream>>>(hi, labels, sq, maxp, minn);
    k_final<<<dim3(BSZ / 256), dim3(256), 0, stream>>>(maxp, minn, sq, sumcnt);
    k_out<<<dim3(1), dim3(64), 0, stream>>>(sumcnt, out);
}